// Round 2
// baseline (668.439 us; speedup 1.0000x reference)
//
#include <hip/hip_runtime.h>

#define D_EMB 768
#define NH 12
#define DK 64
#define NB 2
#define SS 4096
#define E3 (3*D_EMB)   // 2304
#define MM (NB*SS)     // 8192

typedef unsigned short u16;
typedef __attribute__((ext_vector_type(8))) __bf16 bf16x8;
typedef __attribute__((ext_vector_type(4))) float f32x4;
typedef __attribute__((ext_vector_type(4))) unsigned int u32x4;

static __device__ __forceinline__ u16 f2bf(float f) {
  unsigned u = __builtin_bit_cast(unsigned, f);
  u += 0x7fffu + ((u >> 16) & 1u);          // round-to-nearest-even
  return (u16)(u >> 16);
}
static __device__ __forceinline__ f32x4 mfma16(bf16x8 a, bf16x8 b, f32x4 c) {
  return __builtin_amdgcn_mfma_f32_16x16x32_bf16(a, b, c, 0, 0, 0);
}
static __device__ __forceinline__ float exp2_fast(float x) {
#if __has_builtin(__builtin_amdgcn_exp2f)
  return __builtin_amdgcn_exp2f(x);
#else
  return __builtin_exp2f(x);
#endif
}
static __device__ __forceinline__ float rcp_fast(float x) {
#if __has_builtin(__builtin_amdgcn_rcpf)
  return __builtin_amdgcn_rcpf(x);
#else
  return 1.f / x;
#endif
}
static __device__ __forceinline__ void gload_lds16(const u16* g, u16* l) {
  __builtin_amdgcn_global_load_lds((const __attribute__((address_space(1))) void*)g,
                                   (__attribute__((address_space(3))) void*)l, 16, 0, 0);
}

// ---------------- cast fp32 -> bf16, elementwise ----------------
__global__ __launch_bounds__(256) void cast_kernel(const float* __restrict__ in,
                                                   u16* __restrict__ out, int n) {
  int i = (blockIdx.x * 256 + threadIdx.x) * 4;
  if (i + 3 < n) {
    float4 v = *(const float4*)(in + i);
    out[i + 0] = f2bf(v.x);
    out[i + 1] = f2bf(v.y);
    out[i + 2] = f2bf(v.z);
    out[i + 3] = f2bf(v.w);
  }
}

// -------- transpose + cast all four weights (z selects): WT[n][k] = W[k][n] * scale --------
__global__ __launch_bounds__(256) void transpose_cast_all(const float* __restrict__ Wq,
                                                          const float* __restrict__ Wk,
                                                          const float* __restrict__ Wv,
                                                          const float* __restrict__ Wo,
                                                          u16* __restrict__ WTqkv,
                                                          u16* __restrict__ WoT, float qscale) {
  __shared__ float tile[32][33];
  int z = blockIdx.z;
  const float* W = (z == 0) ? Wq : (z == 1) ? Wk : (z == 2) ? Wv : Wo;
  u16* WT = (z < 3) ? WTqkv + (size_t)z * D_EMB * D_EMB : WoT;
  float scale = (z == 0) ? qscale : 1.0f;
  int kb = blockIdx.y * 32, nb = blockIdx.x * 32;
  int tx = threadIdx.x, ty = threadIdx.y;
#pragma unroll
  for (int i = 0; i < 4; i++)
    tile[ty + i * 8][tx] = W[(size_t)(kb + ty + i * 8) * D_EMB + nb + tx];
  __syncthreads();
#pragma unroll
  for (int i = 0; i < 4; i++)
    WT[(size_t)(nb + ty + i * 8) * D_EMB + kb + tx] = f2bf(tile[tx][ty + i * 8] * scale);
}

// -------- transpose V (bf16), pi-permuted columns within each 64-block --------
__global__ __launch_bounds__(256) void transpose_v(const u16* __restrict__ QKV,
                                                   u16* __restrict__ VT) {
  __shared__ u16 tile[32][33];
  int bh = blockIdx.z;
  int b = bh / NH, h = bh % NH;
  int sb = blockIdx.x * 32, db = blockIdx.y * 32;
  int tx = threadIdx.x, ty = threadIdx.y;
  const u16* src = QKV + (size_t)(b * SS) * E3 + 2 * D_EMB + h * DK;
  u16* dst = VT + (size_t)bh * DK * SS;
#pragma unroll
  for (int i = 0; i < 4; i++)
    tile[ty + i * 8][tx] = src[(size_t)(sb + ty + i * 8) * E3 + db + tx];
  __syncthreads();
  int s = sb + tx;
  int k6 = s & 63;
  int p = (s & ~63) | (k6 & 0x23) | ((k6 & 0x0C) << 1) | ((k6 & 0x10) >> 2);
#pragma unroll
  for (int i = 0; i < 4; i++)
    dst[(size_t)(db + ty + i * 8) * SS + p] = tile[tx][ty + i * 8];
}

// ---------------- bf16 GEMM, B given transposed ----------------
template <int OUTF32>
__global__ __launch_bounds__(256) void gemm_bt(const u16* __restrict__ A,
                                               const u16* __restrict__ Bt,
                                               void* __restrict__ Cout,
                                               int M, int N, int K, float scale) {
  __shared__ __align__(16) u16 As[128 * 32];
  __shared__ __align__(16) u16 Bs[128 * 32];
  int tid = threadIdx.x;
  int wave = tid >> 6, lane = tid & 63;
  int g = lane >> 4, nIdx = lane & 15;
  int m0 = blockIdx.y * 128, n0 = blockIdx.x * 128;
  int wm = (wave >> 1) * 64, wn = (wave & 1) * 64;

  f32x4 acc[4][4] = {};

  int row = tid >> 2, co = (tid & 3) * 8;
  int row2 = row + 64;

  for (int k0 = 0; k0 < K; k0 += 32) {
    __syncthreads();
    gload_lds16(A  + (size_t)(m0 + row)  * K + k0 + co, As + row  * 32 + co);
    gload_lds16(Bt + (size_t)(n0 + row)  * K + k0 + co, Bs + row  * 32 + co);
    gload_lds16(A  + (size_t)(m0 + row2) * K + k0 + co, As + row2 * 32 + co);
    gload_lds16(Bt + (size_t)(n0 + row2) * K + k0 + co, Bs + row2 * 32 + co);
    __syncthreads();

    bf16x8 af[4], bfr[4];
#pragma unroll
    for (int i = 0; i < 4; i++)
      af[i] = *(const bf16x8*)(As + (wm + i * 16 + nIdx) * 32 + g * 8);
#pragma unroll
    for (int j = 0; j < 4; j++)
      bfr[j] = *(const bf16x8*)(Bs + (wn + j * 16 + nIdx) * 32 + g * 8);
#pragma unroll
    for (int i = 0; i < 4; i++)
#pragma unroll
      for (int j = 0; j < 4; j++)
        acc[i][j] = mfma16(af[i], bfr[j], acc[i][j]);
  }

#pragma unroll
  for (int i = 0; i < 4; i++)
#pragma unroll
    for (int j = 0; j < 4; j++)
#pragma unroll
      for (int r = 0; r < 4; r++) {
        int rr = m0 + wm + i * 16 + g * 4 + r;
        int cc = n0 + wn + j * 16 + nIdx;
        float v = acc[i][j][r] * scale;
        if (OUTF32)
          ((float*)Cout)[(size_t)rr * N + cc] = v;
        else
          ((u16*)Cout)[(size_t)rr * N + cc] = f2bf(v);
      }
}

// ---------------- flash attention v11 ----------------
// v9's verified compute (64-kv tiles, identical swizzle keys and read
// addressing, bit-identical arithmetic) with the staging SINGLE-buffered
// using the gemm_bt-proven two-barrier structure:
//   for kt: { barrier; stage glls(kt); barrier; compute(kt); }
// Staging LDS drops 64 KB -> 32 KB; block LDS = max(32 KB staging,
// 34 KB merge dump) = 34816 B -> 4 blocks/CU by LDS (grid 768 = 3/CU
// average, all blocks resident, no tail). Prefetch overlap within a block
// is lost; cross-block overlap (12+ waves/CU) hides the staging latency.
__global__ __launch_bounds__(256, 4) void flash(const u16* __restrict__ QKV,
                                                const u16* __restrict__ VT,
                                                u16* __restrict__ O) {
  // staging: [stream 2][K 4096 u16][V 4096 u16] = 16384 u16 (32 KB)
  // merge dump: 128 lanes * 68 f32 = 8704 f32 = 17408 u16 (34 KB)
  __shared__ __align__(16) u16 smem[17408];

  int b = blockIdx.z, h = blockIdx.y;
  int q0 = blockIdx.x * 128;
  int tid = threadIdx.x, w = tid >> 6, l = tid & 63;
  int g = l >> 4, n = l & 15;
  int qh = w & 1, st = w >> 1;

  const u16* VTb = VT + (size_t)(b * NH + h) * DK * SS;
  u16* sbase = smem + st * 8192;              // this stream's buffer

  // --- Q fragments: 64 rows for this wave ---
  const u16* Qbase = QKV + (size_t)(b * SS + q0 + qh * 64) * E3 + h * DK;
  bf16x8 qf[4][2];
#pragma unroll
  for (int qg = 0; qg < 4; qg++)
#pragma unroll
    for (int hf = 0; hf < 2; hf++)
      qf[qg][hf] = *(const bf16x8*)(Qbase + (size_t)(qg * 16 + n) * E3 + hf * 32 + g * 8);

  f32x4 o_acc[4][4] = {};
  float lsum[4] = {0.f, 0.f, 0.f, 0.f};
  u32x4 onev = {0x3F803F80u, 0x3F803F80u, 0x3F803F80u, 0x3F803F80u};
  bf16x8 aone = __builtin_bit_cast(bf16x8, onev);

  // --- staging: even waves stage K of their stream, odd waves stage V ---
  int rL = l >> 3, cL = l & 7;
  int xr8 = (cL ^ rL) * 8;                    // source-side XOR swizzle
  const u16* g0;
  size_t rstep, tstep;
  u16* sd0;                                   // per-lane LDS dest: uniform + l*16B
  if ((w & 1) == 0) {
    g0 = QKV + ((size_t)(b * SS) + st * 2048 + rL) * E3 + D_EMB + h * DK + xr8;
    rstep = (size_t)8 * E3;
    tstep = (size_t)64 * E3;
    sd0 = sbase + l * 8;
  } else {
    g0 = VTb + (size_t)rL * SS + st * 2048 + xr8;
    rstep = (size_t)8 * SS;
    tstep = 64;
    sd0 = sbase + 4096 + l * 8;
  }

  int xrn = (n & 7);
  for (int kt = 0; kt < 32; kt++) {
    __syncthreads();                          // prior tile's reads complete

    const u16* gsrc = g0 + (size_t)kt * tstep;
#pragma unroll
    for (int i = 0; i < 8; i++)
      gload_lds16(gsrc + i * rstep, sd0 + i * 512);

    __syncthreads();                          // staging glls complete & visible

    const u16* pK = sbase;
    const u16* pV = sbase + 4096;

#pragma unroll
    for (int s = 0; s < 2; s++) {             // 32-kv sub-round
      bf16x8 kf[2][2];
#pragma unroll
      for (int jj = 0; jj < 2; jj++)
#pragma unroll
        for (int hf = 0; hf < 2; hf++)
          kf[jj][hf] = *(const bf16x8*)(pK + ((2 * s + jj) * 16 + n) * 64 +
                                        ((hf * 4 + g) ^ xrn) * 8);

#pragma unroll
      for (int p = 0; p < 2; p++) {           // q-group pair
        f32x4 C[2][2];
#pragma unroll
        for (int q2 = 0; q2 < 2; q2++) {
          int qg = 2 * p + q2;
#pragma unroll
          for (int jj = 0; jj < 2; jj++) {
            f32x4 t = {};
            t = mfma16(kf[jj][0], qf[qg][0], t);
            t = mfma16(kf[jj][1], qf[qg][1], t);
            C[q2][jj] = t;
          }
        }
        u32x4 Bw[2];
#pragma unroll
        for (int q2 = 0; q2 < 2; q2++)
#pragma unroll
          for (int jj = 0; jj < 2; jj++) {
            float p0 = exp2_fast(C[q2][jj][0]);
            float p1 = exp2_fast(C[q2][jj][1]);
            float p2 = exp2_fast(C[q2][jj][2]);
            float p3 = exp2_fast(C[q2][jj][3]);
            Bw[q2][jj * 2] = __builtin_amdgcn_perm(__builtin_bit_cast(unsigned, p1),
                                                   __builtin_bit_cast(unsigned, p0), 0x07060302u);
            Bw[q2][jj * 2 + 1] = __builtin_amdgcn_perm(__builtin_bit_cast(unsigned, p3),
                                                       __builtin_bit_cast(unsigned, p2), 0x07060302u);
          }
#pragma unroll
        for (int q2 = 0; q2 < 2; q2++) {
          f32x4 z = {};
          z = mfma16(aone, __builtin_bit_cast(bf16x8, Bw[q2]), z);
          lsum[2 * p + q2] += z[0];
        }
#pragma unroll
        for (int dt = 0; dt < 4; dt++) {
          bf16x8 vf = *(const bf16x8*)(pV + (dt * 16 + n) * 64 +
                                       ((s * 4 + g) ^ xrn) * 8);
#pragma unroll
          for (int q2 = 0; q2 < 2; q2++)
            o_acc[2 * p + q2][dt] = mfma16(vf, __builtin_bit_cast(bf16x8, Bw[q2]),
                                           o_acc[2 * p + q2][dt]);
        }
      }
    }
  }

  __syncthreads();                            // all reads done before dump reuses smem

  // --- cross-wave merge: stream B dumps (O,l), stream A adds & writes ---
  float* dumpF = (float*)smem;
  if (w >= 2) {
    float* dst = dumpF + ((size_t)((w - 2) * 64 + l)) * 68;
#pragma unroll
    for (int qg = 0; qg < 4; qg++)
#pragma unroll
      for (int dt = 0; dt < 4; dt++)
        *(f32x4*)(dst + (qg * 4 + dt) * 4) = o_acc[qg][dt];
    f32x4 lv = {lsum[0], lsum[1], lsum[2], lsum[3]};
    *(f32x4*)(dst + 64) = lv;
  }
  __syncthreads();
  if (w < 2) {
    float* src = dumpF + ((size_t)(w * 64 + l)) * 68;
#pragma unroll
    for (int qg = 0; qg < 4; qg++)
#pragma unroll
      for (int dt = 0; dt < 4; dt++)
        o_acc[qg][dt] += *(f32x4*)(src + (qg * 4 + dt) * 4);
    f32x4 lv = *(f32x4*)(src + 64);
#pragma unroll
    for (int qg = 0; qg < 4; qg++) {
      float rl = rcp_fast(lsum[qg] + lv[qg]);
      u16* Obp = O + (size_t)(b * SS + q0 + w * 64 + qg * 16 + n) * D_EMB + h * DK;
#pragma unroll
      for (int dt = 0; dt < 4; dt++) {
        uint2 pk;
        pk.x = (unsigned)f2bf(o_acc[qg][dt][0] * rl) |
               ((unsigned)f2bf(o_acc[qg][dt][1] * rl) << 16);
        pk.y = (unsigned)f2bf(o_acc[qg][dt][2] * rl) |
               ((unsigned)f2bf(o_acc[qg][dt][3] * rl) << 16);
        *(uint2*)(Obp + dt * 16 + g * 4) = pk;
      }
    }
  }
}

extern "C" void kernel_launch(void* const* d_in, const int* in_sizes, int n_in,
                              void* d_out, int out_size, void* d_ws, size_t ws_size,
                              hipStream_t stream) {
  const float* X  = (const float*)d_in[0];
  const float* Wq = (const float*)d_in[1];
  const float* Wk = (const float*)d_in[2];
  const float* Wv = (const float*)d_in[3];
  const float* Wo = (const float*)d_in[4];
  float* out = (float*)d_out;

  u16* Xb    = (u16*)d_ws;                         // MM*D_EMB
  u16* WTqkv = Xb + (size_t)MM * D_EMB;            // E3*D_EMB
  u16* WoT   = WTqkv + (size_t)E3 * D_EMB;         // D_EMB*D_EMB
  u16* QKV   = WoT + (size_t)D_EMB * D_EMB;        // MM*E3
  u16* VT    = QKV + (size_t)MM * E3;              // NB*NH*DK*SS
  u16* Ob    = VT + (size_t)NB * NH * DK * SS;     // MM*D_EMB

  dim3 tb(32, 8);
  cast_kernel<<<(MM * D_EMB) / 1024, 256, 0, stream>>>(X, Xb, MM * D_EMB);
  transpose_cast_all<<<dim3(24, 24, 4), tb, 0, stream>>>(Wq, Wk, Wv, Wo, WTqkv, WoT,
                                                         0.125f * 1.4426950408889634f);
  gemm_bt<0><<<dim3(E3 / 128, MM / 128), 256, 0, stream>>>(Xb, WTqkv, (void*)QKV,
                                                           MM, E3, D_EMB, 1.0f);
  transpose_v<<<dim3(SS / 32, 2, NB * NH), tb, 0, stream>>>(QKV, VT);
  flash<<<dim3(SS / 128, NH, NB), 256, 0, stream>>>(QKV, VT, Ob);
  gemm_bt<1><<<dim3(D_EMB / 128, MM / 128), 256, 0, stream>>>(Ob, WoT, (void*)out,
                                                              MM, D_EMB, D_EMB, 1.0f);
}

// Round 3
// 286.885 us; speedup vs baseline: 2.3300x; 2.3300x over previous
//
#include <hip/hip_runtime.h>

#define D_EMB 768
#define NH 12
#define DK 64
#define NB 2
#define SS 4096
#define E3 (3*D_EMB)   // 2304
#define MM (NB*SS)     // 8192

typedef unsigned short u16;
typedef __attribute__((ext_vector_type(8))) __bf16 bf16x8;
typedef __attribute__((ext_vector_type(4))) float f32x4;
typedef __attribute__((ext_vector_type(4))) unsigned int u32x4;

static __device__ __forceinline__ u16 f2bf(float f) {
  unsigned u = __builtin_bit_cast(unsigned, f);
  u += 0x7fffu + ((u >> 16) & 1u);          // round-to-nearest-even
  return (u16)(u >> 16);
}
static __device__ __forceinline__ f32x4 mfma16(bf16x8 a, bf16x8 b, f32x4 c) {
  return __builtin_amdgcn_mfma_f32_16x16x32_bf16(a, b, c, 0, 0, 0);
}
static __device__ __forceinline__ float exp2_fast(float x) {
#if __has_builtin(__builtin_amdgcn_exp2f)
  return __builtin_amdgcn_exp2f(x);
#else
  return __builtin_exp2f(x);
#endif
}
static __device__ __forceinline__ float rcp_fast(float x) {
#if __has_builtin(__builtin_amdgcn_rcpf)
  return __builtin_amdgcn_rcpf(x);
#else
  return 1.f / x;
#endif
}
static __device__ __forceinline__ void gload_lds16(const u16* g, u16* l) {
  __builtin_amdgcn_global_load_lds((const __attribute__((address_space(1))) void*)g,
                                   (__attribute__((address_space(3))) void*)l, 16, 0, 0);
}

// ---------------- cast fp32 -> bf16, elementwise ----------------
__global__ __launch_bounds__(256) void cast_kernel(const float* __restrict__ in,
                                                   u16* __restrict__ out, int n) {
  int i = (blockIdx.x * 256 + threadIdx.x) * 4;
  if (i + 3 < n) {
    float4 v = *(const float4*)(in + i);
    out[i + 0] = f2bf(v.x);
    out[i + 1] = f2bf(v.y);
    out[i + 2] = f2bf(v.z);
    out[i + 3] = f2bf(v.w);
  }
}

// -------- transpose + cast all four weights (z selects): WT[n][k] = W[k][n] * scale --------
__global__ __launch_bounds__(256) void transpose_cast_all(const float* __restrict__ Wq,
                                                          const float* __restrict__ Wk,
                                                          const float* __restrict__ Wv,
                                                          const float* __restrict__ Wo,
                                                          u16* __restrict__ WTqkv,
                                                          u16* __restrict__ WoT, float qscale) {
  __shared__ float tile[32][33];
  int z = blockIdx.z;
  const float* W = (z == 0) ? Wq : (z == 1) ? Wk : (z == 2) ? Wv : Wo;
  u16* WT = (z < 3) ? WTqkv + (size_t)z * D_EMB * D_EMB : WoT;
  float scale = (z == 0) ? qscale : 1.0f;
  int kb = blockIdx.y * 32, nb = blockIdx.x * 32;
  int tx = threadIdx.x, ty = threadIdx.y;
#pragma unroll
  for (int i = 0; i < 4; i++)
    tile[ty + i * 8][tx] = W[(size_t)(kb + ty + i * 8) * D_EMB + nb + tx];
  __syncthreads();
#pragma unroll
  for (int i = 0; i < 4; i++)
    WT[(size_t)(nb + ty + i * 8) * D_EMB + kb + tx] = f2bf(tile[tx][ty + i * 8] * scale);
}

// -------- transpose V (bf16), pi-permuted columns within each 64-block --------
__global__ __launch_bounds__(256) void transpose_v(const u16* __restrict__ QKV,
                                                   u16* __restrict__ VT) {
  __shared__ u16 tile[32][33];
  int bh = blockIdx.z;
  int b = bh / NH, h = bh % NH;
  int sb = blockIdx.x * 32, db = blockIdx.y * 32;
  int tx = threadIdx.x, ty = threadIdx.y;
  const u16* src = QKV + (size_t)(b * SS) * E3 + 2 * D_EMB + h * DK;
  u16* dst = VT + (size_t)bh * DK * SS;
#pragma unroll
  for (int i = 0; i < 4; i++)
    tile[ty + i * 8][tx] = src[(size_t)(sb + ty + i * 8) * E3 + db + tx];
  __syncthreads();
  int s = sb + tx;
  int k6 = s & 63;
  int p = (s & ~63) | (k6 & 0x23) | ((k6 & 0x0C) << 1) | ((k6 & 0x10) >> 2);
#pragma unroll
  for (int i = 0; i < 4; i++)
    dst[(size_t)(db + ty + i * 8) * SS + p] = tile[tx][ty + i * 8];
}

// ---------------- bf16 GEMM, B given transposed ----------------
template <int OUTF32>
__global__ __launch_bounds__(256) void gemm_bt(const u16* __restrict__ A,
                                               const u16* __restrict__ Bt,
                                               void* __restrict__ Cout,
                                               int M, int N, int K, float scale) {
  __shared__ __align__(16) u16 As[128 * 32];
  __shared__ __align__(16) u16 Bs[128 * 32];
  int tid = threadIdx.x;
  int wave = tid >> 6, lane = tid & 63;
  int g = lane >> 4, nIdx = lane & 15;
  int m0 = blockIdx.y * 128, n0 = blockIdx.x * 128;
  int wm = (wave >> 1) * 64, wn = (wave & 1) * 64;

  f32x4 acc[4][4] = {};

  int row = tid >> 2, co = (tid & 3) * 8;
  int row2 = row + 64;

  for (int k0 = 0; k0 < K; k0 += 32) {
    __syncthreads();
    gload_lds16(A  + (size_t)(m0 + row)  * K + k0 + co, As + row  * 32 + co);
    gload_lds16(Bt + (size_t)(n0 + row)  * K + k0 + co, Bs + row  * 32 + co);
    gload_lds16(A  + (size_t)(m0 + row2) * K + k0 + co, As + row2 * 32 + co);
    gload_lds16(Bt + (size_t)(n0 + row2) * K + k0 + co, Bs + row2 * 32 + co);
    __syncthreads();

    bf16x8 af[4], bfr[4];
#pragma unroll
    for (int i = 0; i < 4; i++)
      af[i] = *(const bf16x8*)(As + (wm + i * 16 + nIdx) * 32 + g * 8);
#pragma unroll
    for (int j = 0; j < 4; j++)
      bfr[j] = *(const bf16x8*)(Bs + (wn + j * 16 + nIdx) * 32 + g * 8);
#pragma unroll
    for (int i = 0; i < 4; i++)
#pragma unroll
      for (int j = 0; j < 4; j++)
        acc[i][j] = mfma16(af[i], bfr[j], acc[i][j]);
  }

#pragma unroll
  for (int i = 0; i < 4; i++)
#pragma unroll
    for (int j = 0; j < 4; j++)
#pragma unroll
      for (int r = 0; r < 4; r++) {
        int rr = m0 + wm + i * 16 + g * 4 + r;
        int cc = n0 + wn + j * 16 + nIdx;
        float v = acc[i][j][r] * scale;
        if (OUTF32)
          ((float*)Cout)[(size_t)rr * N + cc] = v;
        else
          ((u16*)Cout)[(size_t)rr * N + cc] = f2bf(v);
      }
}

// ---------------- flash attention v12 ----------------
// v11 (single-buffered two-barrier staging, 34816 B LDS, verified correct)
// with the launch-bounds regression fixed: (256,4) had capped the allocator
// at 64 VGPRs -> ~2.3 GB of scratch spill traffic per dispatch (FETCH 1.02GB,
// WRITE 1.29GB, MfmaUtil 9%). (256,2) lets the kernel keep its natural ~104
// VGPRs (<=128, so HW still allows 4 waves/SIMD); LDS 34816 B still allows
// 4 blocks/CU, grid 768 = 3 blocks/CU resident, no tail.
__global__ __launch_bounds__(256, 2) void flash(const u16* __restrict__ QKV,
                                                const u16* __restrict__ VT,
                                                u16* __restrict__ O) {
  // staging: [stream 2][K 4096 u16][V 4096 u16] = 16384 u16 (32 KB)
  // merge dump: 128 lanes * 68 f32 = 8704 f32 = 17408 u16 (34 KB)
  __shared__ __align__(16) u16 smem[17408];

  int b = blockIdx.z, h = blockIdx.y;
  int q0 = blockIdx.x * 128;
  int tid = threadIdx.x, w = tid >> 6, l = tid & 63;
  int g = l >> 4, n = l & 15;
  int qh = w & 1, st = w >> 1;

  const u16* VTb = VT + (size_t)(b * NH + h) * DK * SS;
  u16* sbase = smem + st * 8192;              // this stream's buffer

  // --- Q fragments: 64 rows for this wave ---
  const u16* Qbase = QKV + (size_t)(b * SS + q0 + qh * 64) * E3 + h * DK;
  bf16x8 qf[4][2];
#pragma unroll
  for (int qg = 0; qg < 4; qg++)
#pragma unroll
    for (int hf = 0; hf < 2; hf++)
      qf[qg][hf] = *(const bf16x8*)(Qbase + (size_t)(qg * 16 + n) * E3 + hf * 32 + g * 8);

  f32x4 o_acc[4][4] = {};
  float lsum[4] = {0.f, 0.f, 0.f, 0.f};
  u32x4 onev = {0x3F803F80u, 0x3F803F80u, 0x3F803F80u, 0x3F803F80u};
  bf16x8 aone = __builtin_bit_cast(bf16x8, onev);

  // --- staging: even waves stage K of their stream, odd waves stage V ---
  int rL = l >> 3, cL = l & 7;
  int xr8 = (cL ^ rL) * 8;                    // source-side XOR swizzle
  const u16* g0;
  size_t rstep, tstep;
  u16* sd0;                                   // per-lane LDS dest: uniform + l*16B
  if ((w & 1) == 0) {
    g0 = QKV + ((size_t)(b * SS) + st * 2048 + rL) * E3 + D_EMB + h * DK + xr8;
    rstep = (size_t)8 * E3;
    tstep = (size_t)64 * E3;
    sd0 = sbase + l * 8;
  } else {
    g0 = VTb + (size_t)rL * SS + st * 2048 + xr8;
    rstep = (size_t)8 * SS;
    tstep = 64;
    sd0 = sbase + 4096 + l * 8;
  }

  int xrn = (n & 7);
  for (int kt = 0; kt < 32; kt++) {
    __syncthreads();                          // prior tile's reads complete

    const u16* gsrc = g0 + (size_t)kt * tstep;
#pragma unroll
    for (int i = 0; i < 8; i++)
      gload_lds16(gsrc + i * rstep, sd0 + i * 512);

    __syncthreads();                          // staging glls complete & visible

    const u16* pK = sbase;
    const u16* pV = sbase + 4096;

#pragma unroll
    for (int s = 0; s < 2; s++) {             // 32-kv sub-round
      bf16x8 kf[2][2];
#pragma unroll
      for (int jj = 0; jj < 2; jj++)
#pragma unroll
        for (int hf = 0; hf < 2; hf++)
          kf[jj][hf] = *(const bf16x8*)(pK + ((2 * s + jj) * 16 + n) * 64 +
                                        ((hf * 4 + g) ^ xrn) * 8);

#pragma unroll
      for (int p = 0; p < 2; p++) {           // q-group pair
        f32x4 C[2][2];
#pragma unroll
        for (int q2 = 0; q2 < 2; q2++) {
          int qg = 2 * p + q2;
#pragma unroll
          for (int jj = 0; jj < 2; jj++) {
            f32x4 t = {};
            t = mfma16(kf[jj][0], qf[qg][0], t);
            t = mfma16(kf[jj][1], qf[qg][1], t);
            C[q2][jj] = t;
          }
        }
        u32x4 Bw[2];
#pragma unroll
        for (int q2 = 0; q2 < 2; q2++)
#pragma unroll
          for (int jj = 0; jj < 2; jj++) {
            float p0 = exp2_fast(C[q2][jj][0]);
            float p1 = exp2_fast(C[q2][jj][1]);
            float p2 = exp2_fast(C[q2][jj][2]);
            float p3 = exp2_fast(C[q2][jj][3]);
            Bw[q2][jj * 2] = __builtin_amdgcn_perm(__builtin_bit_cast(unsigned, p1),
                                                   __builtin_bit_cast(unsigned, p0), 0x07060302u);
            Bw[q2][jj * 2 + 1] = __builtin_amdgcn_perm(__builtin_bit_cast(unsigned, p3),
                                                       __builtin_bit_cast(unsigned, p2), 0x07060302u);
          }
#pragma unroll
        for (int q2 = 0; q2 < 2; q2++) {
          f32x4 z = {};
          z = mfma16(aone, __builtin_bit_cast(bf16x8, Bw[q2]), z);
          lsum[2 * p + q2] += z[0];
        }
#pragma unroll
        for (int dt = 0; dt < 4; dt++) {
          bf16x8 vf = *(const bf16x8*)(pV + (dt * 16 + n) * 64 +
                                       ((s * 4 + g) ^ xrn) * 8);
#pragma unroll
          for (int q2 = 0; q2 < 2; q2++)
            o_acc[2 * p + q2][dt] = mfma16(vf, __builtin_bit_cast(bf16x8, Bw[q2]),
                                           o_acc[2 * p + q2][dt]);
        }
      }
    }
  }

  __syncthreads();                            // all reads done before dump reuses smem

  // --- cross-wave merge: stream B dumps (O,l), stream A adds & writes ---
  float* dumpF = (float*)smem;
  if (w >= 2) {
    float* dst = dumpF + ((size_t)((w - 2) * 64 + l)) * 68;
#pragma unroll
    for (int qg = 0; qg < 4; qg++)
#pragma unroll
      for (int dt = 0; dt < 4; dt++)
        *(f32x4*)(dst + (qg * 4 + dt) * 4) = o_acc[qg][dt];
    f32x4 lv = {lsum[0], lsum[1], lsum[2], lsum[3]};
    *(f32x4*)(dst + 64) = lv;
  }
  __syncthreads();
  if (w < 2) {
    float* src = dumpF + ((size_t)(w * 64 + l)) * 68;
#pragma unroll
    for (int qg = 0; qg < 4; qg++)
#pragma unroll
      for (int dt = 0; dt < 4; dt++)
        o_acc[qg][dt] += *(f32x4*)(src + (qg * 4 + dt) * 4);
    f32x4 lv = *(f32x4*)(src + 64);
#pragma unroll
    for (int qg = 0; qg < 4; qg++) {
      float rl = rcp_fast(lsum[qg] + lv[qg]);
      u16* Obp = O + (size_t)(b * SS + q0 + w * 64 + qg * 16 + n) * D_EMB + h * DK;
#pragma unroll
      for (int dt = 0; dt < 4; dt++) {
        uint2 pk;
        pk.x = (unsigned)f2bf(o_acc[qg][dt][0] * rl) |
               ((unsigned)f2bf(o_acc[qg][dt][1] * rl) << 16);
        pk.y = (unsigned)f2bf(o_acc[qg][dt][2] * rl) |
               ((unsigned)f2bf(o_acc[qg][dt][3] * rl) << 16);
        *(uint2*)(Obp + dt * 16 + g * 4) = pk;
      }
    }
  }
}

extern "C" void kernel_launch(void* const* d_in, const int* in_sizes, int n_in,
                              void* d_out, int out_size, void* d_ws, size_t ws_size,
                              hipStream_t stream) {
  const float* X  = (const float*)d_in[0];
  const float* Wq = (const float*)d_in[1];
  const float* Wk = (const float*)d_in[2];
  const float* Wv = (const float*)d_in[3];
  const float* Wo = (const float*)d_in[4];
  float* out = (float*)d_out;

  u16* Xb    = (u16*)d_ws;                         // MM*D_EMB
  u16* WTqkv = Xb + (size_t)MM * D_EMB;            // E3*D_EMB
  u16* WoT   = WTqkv + (size_t)E3 * D_EMB;         // D_EMB*D_EMB
  u16* QKV   = WoT + (size_t)D_EMB * D_EMB;        // MM*E3
  u16* VT    = QKV + (size_t)MM * E3;              // NB*NH*DK*SS
  u16* Ob    = VT + (size_t)NB * NH * DK * SS;     // MM*D_EMB

  dim3 tb(32, 8);
  cast_kernel<<<(MM * D_EMB) / 1024, 256, 0, stream>>>(X, Xb, MM * D_EMB);
  transpose_cast_all<<<dim3(24, 24, 4), tb, 0, stream>>>(Wq, Wk, Wv, Wo, WTqkv, WoT,
                                                         0.125f * 1.4426950408889634f);
  gemm_bt<0><<<dim3(E3 / 128, MM / 128), 256, 0, stream>>>(Xb, WTqkv, (void*)QKV,
                                                           MM, E3, D_EMB, 1.0f);
  transpose_v<<<dim3(SS / 32, 2, NB * NH), tb, 0, stream>>>(QKV, VT);
  flash<<<dim3(SS / 128, NH, NB), 256, 0, stream>>>(QKV, VT, Ob);
  gemm_bt<1><<<dim3(D_EMB / 128, MM / 128), 256, 0, stream>>>(Ob, WoT, (void*)out,
                                                              MM, D_EMB, D_EMB, 1.0f);
}

// Round 4
// 265.940 us; speedup vs baseline: 2.5135x; 1.0788x over previous
//
#include <hip/hip_runtime.h>

#define D_EMB 768
#define NH 12
#define DK 64
#define NB 2
#define SS 4096
#define E3 (3*D_EMB)   // 2304
#define MM (NB*SS)     // 8192

typedef unsigned short u16;
typedef __attribute__((ext_vector_type(8))) __bf16 bf16x8;
typedef __attribute__((ext_vector_type(4))) float f32x4;
typedef __attribute__((ext_vector_type(4))) unsigned int u32x4;

static __device__ __forceinline__ u16 f2bf(float f) {
  unsigned u = __builtin_bit_cast(unsigned, f);
  u += 0x7fffu + ((u >> 16) & 1u);          // round-to-nearest-even
  return (u16)(u >> 16);
}
static __device__ __forceinline__ f32x4 mfma16(bf16x8 a, bf16x8 b, f32x4 c) {
  return __builtin_amdgcn_mfma_f32_16x16x32_bf16(a, b, c, 0, 0, 0);
}
static __device__ __forceinline__ float exp2_fast(float x) {
#if __has_builtin(__builtin_amdgcn_exp2f)
  return __builtin_amdgcn_exp2f(x);
#else
  return __builtin_exp2f(x);
#endif
}
static __device__ __forceinline__ float rcp_fast(float x) {
#if __has_builtin(__builtin_amdgcn_rcpf)
  return __builtin_amdgcn_rcpf(x);
#else
  return 1.f / x;
#endif
}
static __device__ __forceinline__ void gload_lds16(const u16* g, u16* l) {
  __builtin_amdgcn_global_load_lds((const __attribute__((address_space(1))) void*)g,
                                   (__attribute__((address_space(3))) void*)l, 16, 0, 0);
}

// ---------------- cast fp32 -> bf16, elementwise ----------------
__global__ __launch_bounds__(256) void cast_kernel(const float* __restrict__ in,
                                                   u16* __restrict__ out, int n) {
  int i = (blockIdx.x * 256 + threadIdx.x) * 4;
  if (i + 3 < n) {
    float4 v = *(const float4*)(in + i);
    out[i + 0] = f2bf(v.x);
    out[i + 1] = f2bf(v.y);
    out[i + 2] = f2bf(v.z);
    out[i + 3] = f2bf(v.w);
  }
}

// -------- transpose + cast all four weights (z selects): WT[n][k] = W[k][n] * scale --------
__global__ __launch_bounds__(256) void transpose_cast_all(const float* __restrict__ Wq,
                                                          const float* __restrict__ Wk,
                                                          const float* __restrict__ Wv,
                                                          const float* __restrict__ Wo,
                                                          u16* __restrict__ WTqkv,
                                                          u16* __restrict__ WoT, float qscale) {
  __shared__ float tile[32][33];
  int z = blockIdx.z;
  const float* W = (z == 0) ? Wq : (z == 1) ? Wk : (z == 2) ? Wv : Wo;
  u16* WT = (z < 3) ? WTqkv + (size_t)z * D_EMB * D_EMB : WoT;
  float scale = (z == 0) ? qscale : 1.0f;
  int kb = blockIdx.y * 32, nb = blockIdx.x * 32;
  int tx = threadIdx.x, ty = threadIdx.y;
#pragma unroll
  for (int i = 0; i < 4; i++)
    tile[ty + i * 8][tx] = W[(size_t)(kb + ty + i * 8) * D_EMB + nb + tx];
  __syncthreads();
#pragma unroll
  for (int i = 0; i < 4; i++)
    WT[(size_t)(nb + ty + i * 8) * D_EMB + kb + tx] = f2bf(tile[tx][ty + i * 8] * scale);
}

// -------- transpose V (bf16), pi-permuted columns within each 64-block --------
__global__ __launch_bounds__(256) void transpose_v(const u16* __restrict__ QKV,
                                                   u16* __restrict__ VT) {
  __shared__ u16 tile[32][33];
  int bh = blockIdx.z;
  int b = bh / NH, h = bh % NH;
  int sb = blockIdx.x * 32, db = blockIdx.y * 32;
  int tx = threadIdx.x, ty = threadIdx.y;
  const u16* src = QKV + (size_t)(b * SS) * E3 + 2 * D_EMB + h * DK;
  u16* dst = VT + (size_t)bh * DK * SS;
#pragma unroll
  for (int i = 0; i < 4; i++)
    tile[ty + i * 8][tx] = src[(size_t)(sb + ty + i * 8) * E3 + db + tx];
  __syncthreads();
  int s = sb + tx;
  int k6 = s & 63;
  int p = (s & ~63) | (k6 & 0x23) | ((k6 & 0x0C) << 1) | ((k6 & 0x10) >> 2);
#pragma unroll
  for (int i = 0; i < 4; i++)
    dst[(size_t)(db + ty + i * 8) * SS + p] = tile[tx][ty + i * 8];
}

// ---------------- bf16 GEMM, B given transposed ----------------
template <int OUTF32>
__global__ __launch_bounds__(256) void gemm_bt(const u16* __restrict__ A,
                                               const u16* __restrict__ Bt,
                                               void* __restrict__ Cout,
                                               int M, int N, int K, float scale) {
  __shared__ __align__(16) u16 As[128 * 32];
  __shared__ __align__(16) u16 Bs[128 * 32];
  int tid = threadIdx.x;
  int wave = tid >> 6, lane = tid & 63;
  int g = lane >> 4, nIdx = lane & 15;
  int m0 = blockIdx.y * 128, n0 = blockIdx.x * 128;
  int wm = (wave >> 1) * 64, wn = (wave & 1) * 64;

  f32x4 acc[4][4] = {};

  int row = tid >> 2, co = (tid & 3) * 8;
  int row2 = row + 64;

  for (int k0 = 0; k0 < K; k0 += 32) {
    __syncthreads();
    gload_lds16(A  + (size_t)(m0 + row)  * K + k0 + co, As + row  * 32 + co);
    gload_lds16(Bt + (size_t)(n0 + row)  * K + k0 + co, Bs + row  * 32 + co);
    gload_lds16(A  + (size_t)(m0 + row2) * K + k0 + co, As + row2 * 32 + co);
    gload_lds16(Bt + (size_t)(n0 + row2) * K + k0 + co, Bs + row2 * 32 + co);
    __syncthreads();

    bf16x8 af[4], bfr[4];
#pragma unroll
    for (int i = 0; i < 4; i++)
      af[i] = *(const bf16x8*)(As + (wm + i * 16 + nIdx) * 32 + g * 8);
#pragma unroll
    for (int j = 0; j < 4; j++)
      bfr[j] = *(const bf16x8*)(Bs + (wn + j * 16 + nIdx) * 32 + g * 8);
#pragma unroll
    for (int i = 0; i < 4; i++)
#pragma unroll
      for (int j = 0; j < 4; j++)
        acc[i][j] = mfma16(af[i], bfr[j], acc[i][j]);
  }

#pragma unroll
  for (int i = 0; i < 4; i++)
#pragma unroll
    for (int j = 0; j < 4; j++)
#pragma unroll
      for (int r = 0; r < 4; r++) {
        int rr = m0 + wm + i * 16 + g * 4 + r;
        int cc = n0 + wn + j * 16 + nIdx;
        float v = acc[i][j][r] * scale;
        if (OUTF32)
          ((float*)Cout)[(size_t)rr * N + cc] = v;
        else
          ((u16*)Cout)[(size_t)rr * N + cc] = f2bf(v);
      }
}

// ---------------- flash attention v13 ----------------
// v9's compute, bit-identical FP order, with K/V staging split by phase:
//  - K double-buffered (prefetch K(kt+1) during PV phase, as v9)
//  - V single-buffered: issued right after barrier A, consumed only in the
//    PV phase after barrier B -> latency hides under the QK+exp phase
//  - Bw for BOTH 32-kv sub-rounds held in regs across barrier B, so each
//    vf read now feeds all 4 q-groups (vf b128 reads halved vs v9)
// LDS: 2 streams x (K 2x4096 + V 4096) u16 = 24576 u16 = 48 KB
//   -> 3 blocks/CU (160/48), grid 768 = exactly 3/CU, balanced, prefetch kept.
// Hazards: every buffer's writes separated from readers by a barrier; glls
// drain at the issuing wave's next barrier (A for K, B for V).
__global__ __launch_bounds__(256, 2) void flash(const u16* __restrict__ QKV,
                                                const u16* __restrict__ VT,
                                                u16* __restrict__ O) {
  // per stream: Kb0 [0,4096), Kb1 [4096,8192), V [8192,12288) u16
  // merge dump needs 17408 u16 (34816 B) and reuses [0,17408)
  __shared__ __align__(16) u16 smem[24576];

  int b = blockIdx.z, h = blockIdx.y;
  int q0 = blockIdx.x * 128;
  int tid = threadIdx.x, w = tid >> 6, l = tid & 63;
  int g = l >> 4, n = l & 15;
  int qh = w & 1, st = w >> 1;

  const u16* VTb = VT + (size_t)(b * NH + h) * DK * SS;
  u16* sbase = smem + st * 12288;             // this stream's staging region

  // --- Q fragments: 64 rows for this wave ---
  const u16* Qbase = QKV + (size_t)(b * SS + q0 + qh * 64) * E3 + h * DK;
  bf16x8 qf[4][2];
#pragma unroll
  for (int qg = 0; qg < 4; qg++)
#pragma unroll
    for (int hf = 0; hf < 2; hf++)
      qf[qg][hf] = *(const bf16x8*)(Qbase + (size_t)(qg * 16 + n) * E3 + hf * 32 + g * 8);

  f32x4 o_acc[4][4] = {};
  float lsum[4] = {0.f, 0.f, 0.f, 0.f};
  u32x4 onev = {0x3F803F80u, 0x3F803F80u, 0x3F803F80u, 0x3F803F80u};
  bf16x8 aone = __builtin_bit_cast(bf16x8, onev);

  // --- staging: even waves stage K of their stream, odd waves stage V ---
  int rL = l >> 3, cL = l & 7;
  int xr8 = (cL ^ rL) * 8;                    // source-side XOR swizzle
  const u16* g0;
  size_t rstep, tstep;
  u16* sd0;                                   // per-lane LDS dest: uniform + l*16B
  if ((w & 1) == 0) {
    g0 = QKV + ((size_t)(b * SS) + st * 2048 + rL) * E3 + D_EMB + h * DK + xr8;
    rstep = (size_t)8 * E3;
    tstep = (size_t)64 * E3;
    sd0 = sbase + l * 8;                      // + (buf)*4096 at use
  } else {
    g0 = VTb + (size_t)rL * SS + st * 2048 + xr8;
    rstep = (size_t)8 * SS;
    tstep = 64;
    sd0 = sbase + 8192 + l * 8;               // single V buffer
  }

  // prologue: stage K tile 0 into Kbuf 0
  if ((w & 1) == 0) {
#pragma unroll
    for (int i = 0; i < 8; i++)
      gload_lds16(g0 + i * rstep, sd0 + i * 512);
  }

  int xrn = (n & 7);
  for (int kt = 0; kt < 32; kt++) {
    __syncthreads();                          // A: K(kt) ready; V(kt-1) reads done

    if (w & 1) {                              // issue V(kt); hides under QK phase
      const u16* gsrc = g0 + (size_t)kt * tstep;
#pragma unroll
      for (int i = 0; i < 8; i++)
        gload_lds16(gsrc + i * rstep, sd0 + i * 512);
    }

    const u16* pK = sbase + (kt & 1) * 4096;

    // --- QK + exp phase: compute Bw for both 32-kv sub-rounds ---
    u32x4 BwS[2][2][2];
#pragma unroll
    for (int s = 0; s < 2; s++) {
      bf16x8 kf[2][2];
#pragma unroll
      for (int jj = 0; jj < 2; jj++)
#pragma unroll
        for (int hf = 0; hf < 2; hf++)
          kf[jj][hf] = *(const bf16x8*)(pK + ((2 * s + jj) * 16 + n) * 64 +
                                        ((hf * 4 + g) ^ xrn) * 8);

#pragma unroll
      for (int p = 0; p < 2; p++) {
        f32x4 C[2][2];
#pragma unroll
        for (int q2 = 0; q2 < 2; q2++) {
          int qg = 2 * p + q2;
#pragma unroll
          for (int jj = 0; jj < 2; jj++) {
            f32x4 t = {};
            t = mfma16(kf[jj][0], qf[qg][0], t);
            t = mfma16(kf[jj][1], qf[qg][1], t);
            C[q2][jj] = t;
          }
        }
#pragma unroll
        for (int q2 = 0; q2 < 2; q2++)
#pragma unroll
          for (int jj = 0; jj < 2; jj++) {
            float p0 = exp2_fast(C[q2][jj][0]);
            float p1 = exp2_fast(C[q2][jj][1]);
            float p2 = exp2_fast(C[q2][jj][2]);
            float p3 = exp2_fast(C[q2][jj][3]);
            BwS[s][p][q2][jj * 2] = __builtin_amdgcn_perm(__builtin_bit_cast(unsigned, p1),
                                                          __builtin_bit_cast(unsigned, p0), 0x07060302u);
            BwS[s][p][q2][jj * 2 + 1] = __builtin_amdgcn_perm(__builtin_bit_cast(unsigned, p3),
                                                              __builtin_bit_cast(unsigned, p2), 0x07060302u);
          }
      }
    }

    __syncthreads();                          // B: V(kt) glls complete & visible

    if (((w & 1) == 0) && kt < 31) {          // prefetch K(kt+1); hides under PV
      const u16* gsrc = g0 + (size_t)(kt + 1) * tstep;
      u16* sd = sd0 + ((kt + 1) & 1) * 4096;
#pragma unroll
      for (int i = 0; i < 8; i++)
        gload_lds16(gsrc + i * rstep, sd + i * 512);
    }

    const u16* pV = sbase + 8192;

    // --- lsum + PV phase (same per-element FP order as v9) ---
#pragma unroll
    for (int s = 0; s < 2; s++) {
#pragma unroll
      for (int p = 0; p < 2; p++)
#pragma unroll
        for (int q2 = 0; q2 < 2; q2++) {
          f32x4 z = {};
          z = mfma16(aone, __builtin_bit_cast(bf16x8, BwS[s][p][q2]), z);
          lsum[2 * p + q2] += z[0];
        }
#pragma unroll
      for (int dt = 0; dt < 4; dt++) {
        bf16x8 vf = *(const bf16x8*)(pV + (dt * 16 + n) * 64 +
                                     ((s * 4 + g) ^ xrn) * 8);
#pragma unroll
        for (int p = 0; p < 2; p++)
#pragma unroll
          for (int q2 = 0; q2 < 2; q2++)
            o_acc[2 * p + q2][dt] = mfma16(vf, __builtin_bit_cast(bf16x8, BwS[s][p][q2]),
                                           o_acc[2 * p + q2][dt]);
      }
    }
  }

  __syncthreads();                            // all reads done before dump reuses smem

  // --- cross-wave merge: stream B dumps (O,l), stream A adds & writes ---
  float* dumpF = (float*)smem;
  if (w >= 2) {
    float* dst = dumpF + ((size_t)((w - 2) * 64 + l)) * 68;
#pragma unroll
    for (int qg = 0; qg < 4; qg++)
#pragma unroll
      for (int dt = 0; dt < 4; dt++)
        *(f32x4*)(dst + (qg * 4 + dt) * 4) = o_acc[qg][dt];
    f32x4 lv = {lsum[0], lsum[1], lsum[2], lsum[3]};
    *(f32x4*)(dst + 64) = lv;
  }
  __syncthreads();
  if (w < 2) {
    float* src = dumpF + ((size_t)(w * 64 + l)) * 68;
#pragma unroll
    for (int qg = 0; qg < 4; qg++)
#pragma unroll
      for (int dt = 0; dt < 4; dt++)
        o_acc[qg][dt] += *(f32x4*)(src + (qg * 4 + dt) * 4);
    f32x4 lv = *(f32x4*)(src + 64);
#pragma unroll
    for (int qg = 0; qg < 4; qg++) {
      float rl = rcp_fast(lsum[qg] + lv[qg]);
      u16* Obp = O + (size_t)(b * SS + q0 + w * 64 + qg * 16 + n) * D_EMB + h * DK;
#pragma unroll
      for (int dt = 0; dt < 4; dt++) {
        uint2 pk;
        pk.x = (unsigned)f2bf(o_acc[qg][dt][0] * rl) |
               ((unsigned)f2bf(o_acc[qg][dt][1] * rl) << 16);
        pk.y = (unsigned)f2bf(o_acc[qg][dt][2] * rl) |
               ((unsigned)f2bf(o_acc[qg][dt][3] * rl) << 16);
        *(uint2*)(Obp + dt * 16 + g * 4) = pk;
      }
    }
  }
}

extern "C" void kernel_launch(void* const* d_in, const int* in_sizes, int n_in,
                              void* d_out, int out_size, void* d_ws, size_t ws_size,
                              hipStream_t stream) {
  const float* X  = (const float*)d_in[0];
  const float* Wq = (const float*)d_in[1];
  const float* Wk = (const float*)d_in[2];
  const float* Wv = (const float*)d_in[3];
  const float* Wo = (const float*)d_in[4];
  float* out = (float*)d_out;

  u16* Xb    = (u16*)d_ws;                         // MM*D_EMB
  u16* WTqkv = Xb + (size_t)MM * D_EMB;            // E3*D_EMB
  u16* WoT   = WTqkv + (size_t)E3 * D_EMB;         // D_EMB*D_EMB
  u16* QKV   = WoT + (size_t)D_EMB * D_EMB;        // MM*E3
  u16* VT    = QKV + (size_t)MM * E3;              // NB*NH*DK*SS
  u16* Ob    = VT + (size_t)NB * NH * DK * SS;     // MM*D_EMB

  dim3 tb(32, 8);
  cast_kernel<<<(MM * D_EMB) / 1024, 256, 0, stream>>>(X, Xb, MM * D_EMB);
  transpose_cast_all<<<dim3(24, 24, 4), tb, 0, stream>>>(Wq, Wk, Wv, Wo, WTqkv, WoT,
                                                         0.125f * 1.4426950408889634f);
  gemm_bt<0><<<dim3(E3 / 128, MM / 128), 256, 0, stream>>>(Xb, WTqkv, (void*)QKV,
                                                           MM, E3, D_EMB, 1.0f);
  transpose_v<<<dim3(SS / 32, 2, NB * NH), tb, 0, stream>>>(QKV, VT);
  flash<<<dim3(SS / 128, NH, NB), 256, 0, stream>>>(QKV, VT, Ob);
  gemm_bt<1><<<dim3(D_EMB / 128, MM / 128), 256, 0, stream>>>(Ob, WoT, (void*)out,
                                                              MM, D_EMB, D_EMB, 1.0f);
}

// Round 5
// 261.610 us; speedup vs baseline: 2.5551x; 1.0166x over previous
//
#include <hip/hip_runtime.h>

#define D_EMB 768
#define NH 12
#define DK 64
#define NB 2
#define SS 4096
#define E3 (3*D_EMB)   // 2304
#define MM (NB*SS)     // 8192

typedef unsigned short u16;
typedef __attribute__((ext_vector_type(8))) __bf16 bf16x8;
typedef __attribute__((ext_vector_type(4))) float f32x4;
typedef __attribute__((ext_vector_type(4))) unsigned int u32x4;

static __device__ __forceinline__ u16 f2bf(float f) {
  unsigned u = __builtin_bit_cast(unsigned, f);
  u += 0x7fffu + ((u >> 16) & 1u);          // round-to-nearest-even
  return (u16)(u >> 16);
}
static __device__ __forceinline__ f32x4 mfma16(bf16x8 a, bf16x8 b, f32x4 c) {
  return __builtin_amdgcn_mfma_f32_16x16x32_bf16(a, b, c, 0, 0, 0);
}
static __device__ __forceinline__ float exp2_fast(float x) {
#if __has_builtin(__builtin_amdgcn_exp2f)
  return __builtin_amdgcn_exp2f(x);
#else
  return __builtin_exp2f(x);
#endif
}
static __device__ __forceinline__ float rcp_fast(float x) {
#if __has_builtin(__builtin_amdgcn_rcpf)
  return __builtin_amdgcn_rcpf(x);
#else
  return 1.f / x;
#endif
}
static __device__ __forceinline__ void gload_lds16(const u16* g, u16* l) {
  __builtin_amdgcn_global_load_lds((const __attribute__((address_space(1))) void*)g,
                                   (__attribute__((address_space(3))) void*)l, 16, 0, 0);
}

// ---------------- cast fp32 -> bf16, elementwise ----------------
__global__ __launch_bounds__(256) void cast_kernel(const float* __restrict__ in,
                                                   u16* __restrict__ out, int n) {
  int i = (blockIdx.x * 256 + threadIdx.x) * 4;
  if (i + 3 < n) {
    float4 v = *(const float4*)(in + i);
    out[i + 0] = f2bf(v.x);
    out[i + 1] = f2bf(v.y);
    out[i + 2] = f2bf(v.z);
    out[i + 3] = f2bf(v.w);
  }
}

// -------- transpose + cast all four weights (z selects): WT[n][k] = W[k][n] * scale --------
__global__ __launch_bounds__(256) void transpose_cast_all(const float* __restrict__ Wq,
                                                          const float* __restrict__ Wk,
                                                          const float* __restrict__ Wv,
                                                          const float* __restrict__ Wo,
                                                          u16* __restrict__ WTqkv,
                                                          u16* __restrict__ WoT, float qscale) {
  __shared__ float tile[32][33];
  int z = blockIdx.z;
  const float* W = (z == 0) ? Wq : (z == 1) ? Wk : (z == 2) ? Wv : Wo;
  u16* WT = (z < 3) ? WTqkv + (size_t)z * D_EMB * D_EMB : WoT;
  float scale = (z == 0) ? qscale : 1.0f;
  int kb = blockIdx.y * 32, nb = blockIdx.x * 32;
  int tx = threadIdx.x, ty = threadIdx.y;
#pragma unroll
  for (int i = 0; i < 4; i++)
    tile[ty + i * 8][tx] = W[(size_t)(kb + ty + i * 8) * D_EMB + nb + tx];
  __syncthreads();
#pragma unroll
  for (int i = 0; i < 4; i++)
    WT[(size_t)(nb + ty + i * 8) * D_EMB + kb + tx] = f2bf(tile[tx][ty + i * 8] * scale);
}

// -------- transpose V (bf16), pi-permuted columns within each 64-block --------
__global__ __launch_bounds__(256) void transpose_v(const u16* __restrict__ QKV,
                                                   u16* __restrict__ VT) {
  __shared__ u16 tile[32][33];
  int bh = blockIdx.z;
  int b = bh / NH, h = bh % NH;
  int sb = blockIdx.x * 32, db = blockIdx.y * 32;
  int tx = threadIdx.x, ty = threadIdx.y;
  const u16* src = QKV + (size_t)(b * SS) * E3 + 2 * D_EMB + h * DK;
  u16* dst = VT + (size_t)bh * DK * SS;
#pragma unroll
  for (int i = 0; i < 4; i++)
    tile[ty + i * 8][tx] = src[(size_t)(sb + ty + i * 8) * E3 + db + tx];
  __syncthreads();
  int s = sb + tx;
  int k6 = s & 63;
  int p = (s & ~63) | (k6 & 0x23) | ((k6 & 0x0C) << 1) | ((k6 & 0x10) >> 2);
#pragma unroll
  for (int i = 0; i < 4; i++)
    dst[(size_t)(db + ty + i * 8) * SS + p] = tile[tx][ty + i * 8];
}

// ---------------- bf16 GEMM, B given transposed ----------------
// v2: BK 32 -> 64. Halves barrier count (K=768: 24 -> 12 sync pairs) and
// adds flash's proven source-side XOR swizzle so frag ds_read_b128s are
// conflict-free (old 64B-row-stride layout aliased to 2 bank positions).
// LDS[r][c] holds source chunk c^(r&7); reads use chunk (ks*4+g)^(n&7).
// Per-iter: ks=0's 16 MFMAs then ks=1's 16 MFMAs = exactly the same 32-wide
// accumulate sequence as two old BK=32 iterations -> bit-identical output.
// LDS 2x16KB = 32 KB.
template <int OUTF32>
__global__ __launch_bounds__(256) void gemm_bt(const u16* __restrict__ A,
                                               const u16* __restrict__ Bt,
                                               void* __restrict__ Cout,
                                               int M, int N, int K, float scale) {
  __shared__ __align__(16) u16 As[128 * 64];
  __shared__ __align__(16) u16 Bs[128 * 64];
  int tid = threadIdx.x;
  int wave = tid >> 6, lane = tid & 63;
  int g = lane >> 4, nIdx = lane & 15;
  int m0 = blockIdx.y * 128, n0 = blockIdx.x * 128;
  int wm = (wave >> 1) * 64, wn = (wave & 1) * 64;

  f32x4 acc[4][4] = {};

  int rL = lane >> 3, cL = lane & 7;
  int xr8 = (cL ^ rL) * 8;                    // source-side XOR swizzle
  int xrn = nIdx & 7;

  for (int k0 = 0; k0 < K; k0 += 64) {
    __syncthreads();
#pragma unroll
    for (int i = 0; i < 4; i++) {
      int r = (wave * 4 + i) * 8 + rL;        // tile row 0..127
      gload_lds16(A  + (size_t)(m0 + r) * K + k0 + xr8,
                  As + (wave * 4 + i) * 512 + lane * 8);
      gload_lds16(Bt + (size_t)(n0 + r) * K + k0 + xr8,
                  Bs + (wave * 4 + i) * 512 + lane * 8);
    }
    __syncthreads();

#pragma unroll
    for (int ks = 0; ks < 2; ks++) {
      bf16x8 af[4], bfr[4];
#pragma unroll
      for (int i = 0; i < 4; i++)
        af[i] = *(const bf16x8*)(As + (wm + i * 16 + nIdx) * 64 + ((ks * 4 + g) ^ xrn) * 8);
#pragma unroll
      for (int j = 0; j < 4; j++)
        bfr[j] = *(const bf16x8*)(Bs + (wn + j * 16 + nIdx) * 64 + ((ks * 4 + g) ^ xrn) * 8);
#pragma unroll
      for (int i = 0; i < 4; i++)
#pragma unroll
        for (int j = 0; j < 4; j++)
          acc[i][j] = mfma16(af[i], bfr[j], acc[i][j]);
    }
  }

#pragma unroll
  for (int i = 0; i < 4; i++)
#pragma unroll
    for (int j = 0; j < 4; j++)
#pragma unroll
      for (int r = 0; r < 4; r++) {
        int rr = m0 + wm + i * 16 + g * 4 + r;
        int cc = n0 + wn + j * 16 + nIdx;
        float v = acc[i][j][r] * scale;
        if (OUTF32)
          ((float*)Cout)[(size_t)rr * N + cc] = v;
        else
          ((u16*)Cout)[(size_t)rr * N + cc] = f2bf(v);
      }
}

// ---------------- flash attention v9 (reverted to verified best) ----------------
// v8's verified compute (4 waves = q-half x kv-stream, q=64/wave, LDS stream
// merge) with async double-buffered global_load_lds staging:
//  - per-lane LDS dest = base + lane*16B (the gemm_bt-proven gll form)
//  - XOR source swizzle: LDS[r][c] = G[r][c^(r&7)]; reads use (chunk^(n&7))
//  - ONE barrier per ktile; prefetch glls fly across the whole compute phase
// Round 1-4 lesson: 2-barrier variants (single-buffer, K/V phase-split) all
// regress (117-137us vs 109.6); occupancy is pinned ~17.6% regardless of
// blocks/CU -> barrier count per tile is the lever, and 1 is the minimum.
__global__ __launch_bounds__(256, 2) void flash(const u16* __restrict__ QKV,
                                                const u16* __restrict__ VT,
                                                u16* __restrict__ O) {
  // [stream][buf][K 4096 u16][V 4096 u16] = 32768 u16 = 64 KB
  __shared__ __align__(16) u16 smem[32768];

  int b = blockIdx.z, h = blockIdx.y;
  int q0 = blockIdx.x * 128;
  int tid = threadIdx.x, w = tid >> 6, l = tid & 63;
  int g = l >> 4, n = l & 15;
  int qh = w & 1, st = w >> 1;

  const u16* VTb = VT + (size_t)(b * NH + h) * DK * SS;
  u16* sbase = smem + st * 16384;             // this stream's double buffer

  // --- Q fragments: 64 rows for this wave ---
  const u16* Qbase = QKV + (size_t)(b * SS + q0 + qh * 64) * E3 + h * DK;
  bf16x8 qf[4][2];
#pragma unroll
  for (int qg = 0; qg < 4; qg++)
#pragma unroll
    for (int hf = 0; hf < 2; hf++)
      qf[qg][hf] = *(const bf16x8*)(Qbase + (size_t)(qg * 16 + n) * E3 + hf * 32 + g * 8);

  f32x4 o_acc[4][4] = {};
  float lsum[4] = {0.f, 0.f, 0.f, 0.f};
  u32x4 onev = {0x3F803F80u, 0x3F803F80u, 0x3F803F80u, 0x3F803F80u};
  bf16x8 aone = __builtin_bit_cast(bf16x8, onev);

  // --- staging: even waves stage K of their stream, odd waves stage V ---
  int rL = l >> 3, cL = l & 7;
  int xr8 = (cL ^ rL) * 8;                    // source-side XOR swizzle
  const u16* g0;
  size_t rstep, tstep;
  u16* sd0;                                   // per-lane LDS dest: uniform + l*16B
  if ((w & 1) == 0) {
    g0 = QKV + ((size_t)(b * SS) + st * 2048 + rL) * E3 + D_EMB + h * DK + xr8;
    rstep = (size_t)8 * E3;
    tstep = (size_t)64 * E3;
    sd0 = sbase + l * 8;
  } else {
    g0 = VTb + (size_t)rL * SS + st * 2048 + xr8;
    rstep = (size_t)8 * SS;
    tstep = 64;
    sd0 = sbase + 4096 + l * 8;
  }

  // prologue: stage tile 0 into buffer 0
#pragma unroll
  for (int i = 0; i < 8; i++)
    gload_lds16(g0 + i * rstep, sd0 + i * 512);

  int xrn = (n & 7);
  for (int kt = 0; kt < 32; kt++) {
    __syncthreads();                          // buf[kt&1] glls complete & visible

    const u16* pK = sbase + (kt & 1) * 8192;
    const u16* pV = pK + 4096;

    if (kt < 31) {                            // async prefetch into buf[(kt+1)&1]
      const u16* gn = g0 + (size_t)(kt + 1) * tstep;
      u16* sd = sd0 + ((kt + 1) & 1) * 8192;
#pragma unroll
      for (int i = 0; i < 8; i++)
        gload_lds16(gn + i * rstep, sd + i * 512);
    }

#pragma unroll
    for (int s = 0; s < 2; s++) {             // 32-kv sub-round
      bf16x8 kf[2][2];
#pragma unroll
      for (int jj = 0; jj < 2; jj++)
#pragma unroll
        for (int hf = 0; hf < 2; hf++)
          kf[jj][hf] = *(const bf16x8*)(pK + ((2 * s + jj) * 16 + n) * 64 +
                                        ((hf * 4 + g) ^ xrn) * 8);

#pragma unroll
      for (int p = 0; p < 2; p++) {           // q-group pair
        f32x4 C[2][2];
#pragma unroll
        for (int q2 = 0; q2 < 2; q2++) {
          int qg = 2 * p + q2;
#pragma unroll
          for (int jj = 0; jj < 2; jj++) {
            f32x4 t = {};
            t = mfma16(kf[jj][0], qf[qg][0], t);
            t = mfma16(kf[jj][1], qf[qg][1], t);
            C[q2][jj] = t;
          }
        }
        u32x4 Bw[2];
#pragma unroll
        for (int q2 = 0; q2 < 2; q2++)
#pragma unroll
          for (int jj = 0; jj < 2; jj++) {
            float p0 = exp2_fast(C[q2][jj][0]);
            float p1 = exp2_fast(C[q2][jj][1]);
            float p2 = exp2_fast(C[q2][jj][2]);
            float p3 = exp2_fast(C[q2][jj][3]);
            Bw[q2][jj * 2] = __builtin_amdgcn_perm(__builtin_bit_cast(unsigned, p1),
                                                   __builtin_bit_cast(unsigned, p0), 0x07060302u);
            Bw[q2][jj * 2 + 1] = __builtin_amdgcn_perm(__builtin_bit_cast(unsigned, p3),
                                                       __builtin_bit_cast(unsigned, p2), 0x07060302u);
          }
#pragma unroll
        for (int q2 = 0; q2 < 2; q2++) {
          f32x4 z = {};
          z = mfma16(aone, __builtin_bit_cast(bf16x8, Bw[q2]), z);
          lsum[2 * p + q2] += z[0];
        }
#pragma unroll
        for (int dt = 0; dt < 4; dt++) {
          bf16x8 vf = *(const bf16x8*)(pV + (dt * 16 + n) * 64 +
                                       ((s * 4 + g) ^ xrn) * 8);
#pragma unroll
          for (int q2 = 0; q2 < 2; q2++)
            o_acc[2 * p + q2][dt] = mfma16(vf, __builtin_bit_cast(bf16x8, Bw[q2]),
                                           o_acc[2 * p + q2][dt]);
        }
      }
    }
  }

  __syncthreads();                            // all reads done before dump reuses smem

  // --- cross-wave merge: stream B dumps (O,l), stream A adds & writes ---
  float* dumpF = (float*)smem;
  if (w >= 2) {
    float* dst = dumpF + ((size_t)((w - 2) * 64 + l)) * 68;
#pragma unroll
    for (int qg = 0; qg < 4; qg++)
#pragma unroll
      for (int dt = 0; dt < 4; dt++)
        *(f32x4*)(dst + (qg * 4 + dt) * 4) = o_acc[qg][dt];
    f32x4 lv = {lsum[0], lsum[1], lsum[2], lsum[3]};
    *(f32x4*)(dst + 64) = lv;
  }
  __syncthreads();
  if (w < 2) {
    float* src = dumpF + ((size_t)(w * 64 + l)) * 68;
#pragma unroll
    for (int qg = 0; qg < 4; qg++)
#pragma unroll
      for (int dt = 0; dt < 4; dt++)
        o_acc[qg][dt] += *(f32x4*)(src + (qg * 4 + dt) * 4);
    f32x4 lv = *(f32x4*)(src + 64);
#pragma unroll
    for (int qg = 0; qg < 4; qg++) {
      float rl = rcp_fast(lsum[qg] + lv[qg]);
      u16* Obp = O + (size_t)(b * SS + q0 + w * 64 + qg * 16 + n) * D_EMB + h * DK;
#pragma unroll
      for (int dt = 0; dt < 4; dt++) {
        uint2 pk;
        pk.x = (unsigned)f2bf(o_acc[qg][dt][0] * rl) |
               ((unsigned)f2bf(o_acc[qg][dt][1] * rl) << 16);
        pk.y = (unsigned)f2bf(o_acc[qg][dt][2] * rl) |
               ((unsigned)f2bf(o_acc[qg][dt][3] * rl) << 16);
        *(uint2*)(Obp + dt * 16 + g * 4) = pk;
      }
    }
  }
}

extern "C" void kernel_launch(void* const* d_in, const int* in_sizes, int n_in,
                              void* d_out, int out_size, void* d_ws, size_t ws_size,
                              hipStream_t stream) {
  const float* X  = (const float*)d_in[0];
  const float* Wq = (const float*)d_in[1];
  const float* Wk = (const float*)d_in[2];
  const float* Wv = (const float*)d_in[3];
  const float* Wo = (const float*)d_in[4];
  float* out = (float*)d_out;

  u16* Xb    = (u16*)d_ws;                         // MM*D_EMB
  u16* WTqkv = Xb + (size_t)MM * D_EMB;            // E3*D_EMB
  u16* WoT   = WTqkv + (size_t)E3 * D_EMB;         // D_EMB*D_EMB
  u16* QKV   = WoT + (size_t)D_EMB * D_EMB;        // MM*E3
  u16* VT    = QKV + (size_t)MM * E3;              // NB*NH*DK*SS
  u16* Ob    = VT + (size_t)NB * NH * DK * SS;     // MM*D_EMB

  dim3 tb(32, 8);
  cast_kernel<<<(MM * D_EMB) / 1024, 256, 0, stream>>>(X, Xb, MM * D_EMB);
  transpose_cast_all<<<dim3(24, 24, 4), tb, 0, stream>>>(Wq, Wk, Wv, Wo, WTqkv, WoT,
                                                         0.125f * 1.4426950408889634f);
  gemm_bt<0><<<dim3(E3 / 128, MM / 128), 256, 0, stream>>>(Xb, WTqkv, (void*)QKV,
                                                           MM, E3, D_EMB, 1.0f);
  transpose_v<<<dim3(SS / 32, 2, NB * NH), tb, 0, stream>>>(QKV, VT);
  flash<<<dim3(SS / 128, NH, NB), 256, 0, stream>>>(QKV, VT, Ob);
  gemm_bt<1><<<dim3(D_EMB / 128, MM / 128), 256, 0, stream>>>(Ob, WoT, (void*)out,
                                                              MM, D_EMB, D_EMB, 1.0f);
}

// Round 6
// 255.168 us; speedup vs baseline: 2.6196x; 1.0252x over previous
//
#include <hip/hip_runtime.h>

#define D_EMB 768
#define NH 12
#define DK 64
#define NB 2
#define SS 4096
#define E3 (3*D_EMB)   // 2304
#define MM (NB*SS)     // 8192

typedef unsigned short u16;
typedef __attribute__((ext_vector_type(8))) __bf16 bf16x8;
typedef __attribute__((ext_vector_type(4))) float f32x4;
typedef __attribute__((ext_vector_type(4))) unsigned int u32x4;

static __device__ __forceinline__ u16 f2bf(float f) {
  unsigned u = __builtin_bit_cast(unsigned, f);
  u += 0x7fffu + ((u >> 16) & 1u);          // round-to-nearest-even
  return (u16)(u >> 16);
}
static __device__ __forceinline__ f32x4 mfma16(bf16x8 a, bf16x8 b, f32x4 c) {
  return __builtin_amdgcn_mfma_f32_16x16x32_bf16(a, b, c, 0, 0, 0);
}
static __device__ __forceinline__ float exp2_fast(float x) {
#if __has_builtin(__builtin_amdgcn_exp2f)
  return __builtin_amdgcn_exp2f(x);
#else
  return __builtin_exp2f(x);
#endif
}
static __device__ __forceinline__ float rcp_fast(float x) {
#if __has_builtin(__builtin_amdgcn_rcpf)
  return __builtin_amdgcn_rcpf(x);
#else
  return 1.f / x;
#endif
}
static __device__ __forceinline__ void gload_lds16(const u16* g, u16* l) {
  __builtin_amdgcn_global_load_lds((const __attribute__((address_space(1))) void*)g,
                                   (__attribute__((address_space(3))) void*)l, 16, 0, 0);
}

// ---------------- cast fp32 -> bf16, elementwise ----------------
__global__ __launch_bounds__(256) void cast_kernel(const float* __restrict__ in,
                                                   u16* __restrict__ out, int n) {
  int i = (blockIdx.x * 256 + threadIdx.x) * 4;
  if (i + 3 < n) {
    float4 v = *(const float4*)(in + i);
    out[i + 0] = f2bf(v.x);
    out[i + 1] = f2bf(v.y);
    out[i + 2] = f2bf(v.z);
    out[i + 3] = f2bf(v.w);
  }
}

// -------- transpose + cast all four weights (z selects): WT[n][k] = W[k][n] * scale --------
__global__ __launch_bounds__(256) void transpose_cast_all(const float* __restrict__ Wq,
                                                          const float* __restrict__ Wk,
                                                          const float* __restrict__ Wv,
                                                          const float* __restrict__ Wo,
                                                          u16* __restrict__ WTqkv,
                                                          u16* __restrict__ WoT, float qscale) {
  __shared__ float tile[32][33];
  int z = blockIdx.z;
  const float* W = (z == 0) ? Wq : (z == 1) ? Wk : (z == 2) ? Wv : Wo;
  u16* WT = (z < 3) ? WTqkv + (size_t)z * D_EMB * D_EMB : WoT;
  float scale = (z == 0) ? qscale : 1.0f;
  int kb = blockIdx.y * 32, nb = blockIdx.x * 32;
  int tx = threadIdx.x, ty = threadIdx.y;
#pragma unroll
  for (int i = 0; i < 4; i++)
    tile[ty + i * 8][tx] = W[(size_t)(kb + ty + i * 8) * D_EMB + nb + tx];
  __syncthreads();
#pragma unroll
  for (int i = 0; i < 4; i++)
    WT[(size_t)(nb + ty + i * 8) * D_EMB + kb + tx] = f2bf(tile[tx][ty + i * 8] * scale);
}

// -------- transpose V (bf16), pi-permuted columns within each 64-block --------
__global__ __launch_bounds__(256) void transpose_v(const u16* __restrict__ QKV,
                                                   u16* __restrict__ VT) {
  __shared__ u16 tile[32][33];
  int bh = blockIdx.z;
  int b = bh / NH, h = bh % NH;
  int sb = blockIdx.x * 32, db = blockIdx.y * 32;
  int tx = threadIdx.x, ty = threadIdx.y;
  const u16* src = QKV + (size_t)(b * SS) * E3 + 2 * D_EMB + h * DK;
  u16* dst = VT + (size_t)bh * DK * SS;
#pragma unroll
  for (int i = 0; i < 4; i++)
    tile[ty + i * 8][tx] = src[(size_t)(sb + ty + i * 8) * E3 + db + tx];
  __syncthreads();
  int s = sb + tx;
  int k6 = s & 63;
  int p = (s & ~63) | (k6 & 0x23) | ((k6 & 0x0C) << 1) | ((k6 & 0x10) >> 2);
#pragma unroll
  for (int i = 0; i < 4; i++)
    dst[(size_t)(db + ty + i * 8) * SS + p] = tile[tx][ty + i * 8];
}

// ---------------- bf16 GEMM, B given transposed ----------------
// v3: BK=64 + XOR swizzle (v2, verified) restructured to flash's proven
// single-barrier double-buffered schedule:
//   prologue: stage K-tile 0 -> buf0
//   loop kt:  barrier (buf[kt&1] glls drained; buf[kt&1^1]'s old readers done)
//             prefetch K-tile kt+1 -> buf[(kt+1)&1]   (flies across compute)
//             compute kt from buf[kt&1]
// Round-5 lesson: the 2-barrier structure exposed a full staging round-trip
// on each of the 12 K-steps (K=768), pinning the gemms at ~350 TF. Same
// staging map and read addressing as v2; identical MFMA accumulate order
// -> bit-identical output. LDS 2 x (128x64) x 2 arrays = 64 KB.
template <int OUTF32>
__global__ __launch_bounds__(256) void gemm_bt(const u16* __restrict__ A,
                                               const u16* __restrict__ Bt,
                                               void* __restrict__ Cout,
                                               int M, int N, int K, float scale) {
  __shared__ __align__(16) u16 As[2 * 128 * 64];
  __shared__ __align__(16) u16 Bs[2 * 128 * 64];
  int tid = threadIdx.x;
  int wave = tid >> 6, lane = tid & 63;
  int g = lane >> 4, nIdx = lane & 15;
  int m0 = blockIdx.y * 128, n0 = blockIdx.x * 128;
  int wm = (wave >> 1) * 64, wn = (wave & 1) * 64;

  f32x4 acc[4][4] = {};

  int rL = lane >> 3, cL = lane & 7;
  int xr8 = (cL ^ rL) * 8;                    // source-side XOR swizzle
  int xrn = nIdx & 7;
  int nk = K >> 6;

  // prologue: stage K-tile 0 into buf 0
#pragma unroll
  for (int i = 0; i < 4; i++) {
    int r = (wave * 4 + i) * 8 + rL;          // tile row 0..127
    gload_lds16(A  + (size_t)(m0 + r) * K + xr8,
                As + (wave * 4 + i) * 512 + lane * 8);
    gload_lds16(Bt + (size_t)(n0 + r) * K + xr8,
                Bs + (wave * 4 + i) * 512 + lane * 8);
  }

  for (int kt = 0; kt < nk; kt++) {
    __syncthreads();                          // buf[kt&1] glls complete & visible

    int cb = (kt & 1) * 8192;

    if (kt + 1 < nk) {                        // async prefetch into buf[(kt+1)&1]
      int nb = ((kt + 1) & 1) * 8192;
      int k0n = (kt + 1) << 6;
#pragma unroll
      for (int i = 0; i < 4; i++) {
        int r = (wave * 4 + i) * 8 + rL;
        gload_lds16(A  + (size_t)(m0 + r) * K + k0n + xr8,
                    As + nb + (wave * 4 + i) * 512 + lane * 8);
        gload_lds16(Bt + (size_t)(n0 + r) * K + k0n + xr8,
                    Bs + nb + (wave * 4 + i) * 512 + lane * 8);
      }
    }

#pragma unroll
    for (int ks = 0; ks < 2; ks++) {
      bf16x8 af[4], bfr[4];
#pragma unroll
      for (int i = 0; i < 4; i++)
        af[i] = *(const bf16x8*)(As + cb + (wm + i * 16 + nIdx) * 64 + ((ks * 4 + g) ^ xrn) * 8);
#pragma unroll
      for (int j = 0; j < 4; j++)
        bfr[j] = *(const bf16x8*)(Bs + cb + (wn + j * 16 + nIdx) * 64 + ((ks * 4 + g) ^ xrn) * 8);
#pragma unroll
      for (int i = 0; i < 4; i++)
#pragma unroll
        for (int j = 0; j < 4; j++)
          acc[i][j] = mfma16(af[i], bfr[j], acc[i][j]);
    }
  }

#pragma unroll
  for (int i = 0; i < 4; i++)
#pragma unroll
    for (int j = 0; j < 4; j++)
#pragma unroll
      for (int r = 0; r < 4; r++) {
        int rr = m0 + wm + i * 16 + g * 4 + r;
        int cc = n0 + wn + j * 16 + nIdx;
        float v = acc[i][j][r] * scale;
        if (OUTF32)
          ((float*)Cout)[(size_t)rr * N + cc] = v;
        else
          ((u16*)Cout)[(size_t)rr * N + cc] = f2bf(v);
      }
}

// ---------------- flash attention v9 (verified best) ----------------
// v8's verified compute (4 waves = q-half x kv-stream, q=64/wave, LDS stream
// merge) with async double-buffered global_load_lds staging:
//  - per-lane LDS dest = base + lane*16B (the gemm_bt-proven gll form)
//  - XOR source swizzle: LDS[r][c] = G[r][c^(r&7)]; reads use (chunk^(n&7))
//  - ONE barrier per ktile; prefetch glls fly across the whole compute phase
// Round 1-4 lesson: 2-barrier variants (single-buffer, K/V phase-split) all
// regress (117-137us vs 109.6); occupancy is pinned ~17.6% regardless of
// blocks/CU -> barrier count per tile is the lever, and 1 is the minimum.
__global__ __launch_bounds__(256, 2) void flash(const u16* __restrict__ QKV,
                                                const u16* __restrict__ VT,
                                                u16* __restrict__ O) {
  // [stream][buf][K 4096 u16][V 4096 u16] = 32768 u16 = 64 KB
  __shared__ __align__(16) u16 smem[32768];

  int b = blockIdx.z, h = blockIdx.y;
  int q0 = blockIdx.x * 128;
  int tid = threadIdx.x, w = tid >> 6, l = tid & 63;
  int g = l >> 4, n = l & 15;
  int qh = w & 1, st = w >> 1;

  const u16* VTb = VT + (size_t)(b * NH + h) * DK * SS;
  u16* sbase = smem + st * 16384;             // this stream's double buffer

  // --- Q fragments: 64 rows for this wave ---
  const u16* Qbase = QKV + (size_t)(b * SS + q0 + qh * 64) * E3 + h * DK;
  bf16x8 qf[4][2];
#pragma unroll
  for (int qg = 0; qg < 4; qg++)
#pragma unroll
    for (int hf = 0; hf < 2; hf++)
      qf[qg][hf] = *(const bf16x8*)(Qbase + (size_t)(qg * 16 + n) * E3 + hf * 32 + g * 8);

  f32x4 o_acc[4][4] = {};
  float lsum[4] = {0.f, 0.f, 0.f, 0.f};
  u32x4 onev = {0x3F803F80u, 0x3F803F80u, 0x3F803F80u, 0x3F803F80u};
  bf16x8 aone = __builtin_bit_cast(bf16x8, onev);

  // --- staging: even waves stage K of their stream, odd waves stage V ---
  int rL = l >> 3, cL = l & 7;
  int xr8 = (cL ^ rL) * 8;                    // source-side XOR swizzle
  const u16* g0;
  size_t rstep, tstep;
  u16* sd0;                                   // per-lane LDS dest: uniform + l*16B
  if ((w & 1) == 0) {
    g0 = QKV + ((size_t)(b * SS) + st * 2048 + rL) * E3 + D_EMB + h * DK + xr8;
    rstep = (size_t)8 * E3;
    tstep = (size_t)64 * E3;
    sd0 = sbase + l * 8;
  } else {
    g0 = VTb + (size_t)rL * SS + st * 2048 + xr8;
    rstep = (size_t)8 * SS;
    tstep = 64;
    sd0 = sbase + 4096 + l * 8;
  }

  // prologue: stage tile 0 into buffer 0
#pragma unroll
  for (int i = 0; i < 8; i++)
    gload_lds16(g0 + i * rstep, sd0 + i * 512);

  int xrn = (n & 7);
  for (int kt = 0; kt < 32; kt++) {
    __syncthreads();                          // buf[kt&1] glls complete & visible

    const u16* pK = sbase + (kt & 1) * 8192;
    const u16* pV = pK + 4096;

    if (kt < 31) {                            // async prefetch into buf[(kt+1)&1]
      const u16* gn = g0 + (size_t)(kt + 1) * tstep;
      u16* sd = sd0 + ((kt + 1) & 1) * 8192;
#pragma unroll
      for (int i = 0; i < 8; i++)
        gload_lds16(gn + i * rstep, sd + i * 512);
    }

#pragma unroll
    for (int s = 0; s < 2; s++) {             // 32-kv sub-round
      bf16x8 kf[2][2];
#pragma unroll
      for (int jj = 0; jj < 2; jj++)
#pragma unroll
        for (int hf = 0; hf < 2; hf++)
          kf[jj][hf] = *(const bf16x8*)(pK + ((2 * s + jj) * 16 + n) * 64 +
                                        ((hf * 4 + g) ^ xrn) * 8);

#pragma unroll
      for (int p = 0; p < 2; p++) {           // q-group pair
        f32x4 C[2][2];
#pragma unroll
        for (int q2 = 0; q2 < 2; q2++) {
          int qg = 2 * p + q2;
#pragma unroll
          for (int jj = 0; jj < 2; jj++) {
            f32x4 t = {};
            t = mfma16(kf[jj][0], qf[qg][0], t);
            t = mfma16(kf[jj][1], qf[qg][1], t);
            C[q2][jj] = t;
          }
        }
        u32x4 Bw[2];
#pragma unroll
        for (int q2 = 0; q2 < 2; q2++)
#pragma unroll
          for (int jj = 0; jj < 2; jj++) {
            float p0 = exp2_fast(C[q2][jj][0]);
            float p1 = exp2_fast(C[q2][jj][1]);
            float p2 = exp2_fast(C[q2][jj][2]);
            float p3 = exp2_fast(C[q2][jj][3]);
            Bw[q2][jj * 2] = __builtin_amdgcn_perm(__builtin_bit_cast(unsigned, p1),
                                                   __builtin_bit_cast(unsigned, p0), 0x07060302u);
            Bw[q2][jj * 2 + 1] = __builtin_amdgcn_perm(__builtin_bit_cast(unsigned, p3),
                                                       __builtin_bit_cast(unsigned, p2), 0x07060302u);
          }
#pragma unroll
        for (int q2 = 0; q2 < 2; q2++) {
          f32x4 z = {};
          z = mfma16(aone, __builtin_bit_cast(bf16x8, Bw[q2]), z);
          lsum[2 * p + q2] += z[0];
        }
#pragma unroll
        for (int dt = 0; dt < 4; dt++) {
          bf16x8 vf = *(const bf16x8*)(pV + (dt * 16 + n) * 64 +
                                       ((s * 4 + g) ^ xrn) * 8);
#pragma unroll
          for (int q2 = 0; q2 < 2; q2++)
            o_acc[2 * p + q2][dt] = mfma16(vf, __builtin_bit_cast(bf16x8, Bw[q2]),
                                           o_acc[2 * p + q2][dt]);
        }
      }
    }
  }

  __syncthreads();                            // all reads done before dump reuses smem

  // --- cross-wave merge: stream B dumps (O,l), stream A adds & writes ---
  float* dumpF = (float*)smem;
  if (w >= 2) {
    float* dst = dumpF + ((size_t)((w - 2) * 64 + l)) * 68;
#pragma unroll
    for (int qg = 0; qg < 4; qg++)
#pragma unroll
      for (int dt = 0; dt < 4; dt++)
        *(f32x4*)(dst + (qg * 4 + dt) * 4) = o_acc[qg][dt];
    f32x4 lv = {lsum[0], lsum[1], lsum[2], lsum[3]};
    *(f32x4*)(dst + 64) = lv;
  }
  __syncthreads();
  if (w < 2) {
    float* src = dumpF + ((size_t)(w * 64 + l)) * 68;
#pragma unroll
    for (int qg = 0; qg < 4; qg++)
#pragma unroll
      for (int dt = 0; dt < 4; dt++)
        o_acc[qg][dt] += *(f32x4*)(src + (qg * 4 + dt) * 4);
    f32x4 lv = *(f32x4*)(src + 64);
#pragma unroll
    for (int qg = 0; qg < 4; qg++) {
      float rl = rcp_fast(lsum[qg] + lv[qg]);
      u16* Obp = O + (size_t)(b * SS + q0 + w * 64 + qg * 16 + n) * D_EMB + h * DK;
#pragma unroll
      for (int dt = 0; dt < 4; dt++) {
        uint2 pk;
        pk.x = (unsigned)f2bf(o_acc[qg][dt][0] * rl) |
               ((unsigned)f2bf(o_acc[qg][dt][1] * rl) << 16);
        pk.y = (unsigned)f2bf(o_acc[qg][dt][2] * rl) |
               ((unsigned)f2bf(o_acc[qg][dt][3] * rl) << 16);
        *(uint2*)(Obp + dt * 16 + g * 4) = pk;
      }
    }
  }
}

extern "C" void kernel_launch(void* const* d_in, const int* in_sizes, int n_in,
                              void* d_out, int out_size, void* d_ws, size_t ws_size,
                              hipStream_t stream) {
  const float* X  = (const float*)d_in[0];
  const float* Wq = (const float*)d_in[1];
  const float* Wk = (const float*)d_in[2];
  const float* Wv = (const float*)d_in[3];
  const float* Wo = (const float*)d_in[4];
  float* out = (float*)d_out;

  u16* Xb    = (u16*)d_ws;                         // MM*D_EMB
  u16* WTqkv = Xb + (size_t)MM * D_EMB;            // E3*D_EMB
  u16* WoT   = WTqkv + (size_t)E3 * D_EMB;         // D_EMB*D_EMB
  u16* QKV   = WoT + (size_t)D_EMB * D_EMB;        // MM*E3
  u16* VT    = QKV + (size_t)MM * E3;              // NB*NH*DK*SS
  u16* Ob    = VT + (size_t)NB * NH * DK * SS;     // MM*D_EMB

  dim3 tb(32, 8);
  cast_kernel<<<(MM * D_EMB) / 1024, 256, 0, stream>>>(X, Xb, MM * D_EMB);
  transpose_cast_all<<<dim3(24, 24, 4), tb, 0, stream>>>(Wq, Wk, Wv, Wo, WTqkv, WoT,
                                                         0.125f * 1.4426950408889634f);
  gemm_bt<0><<<dim3(E3 / 128, MM / 128), 256, 0, stream>>>(Xb, WTqkv, (void*)QKV,
                                                           MM, E3, D_EMB, 1.0f);
  transpose_v<<<dim3(SS / 32, 2, NB * NH), tb, 0, stream>>>(QKV, VT);
  flash<<<dim3(SS / 128, NH, NB), 256, 0, stream>>>(QKV, VT, Ob);
  gemm_bt<1><<<dim3(D_EMB / 128, MM / 128), 256, 0, stream>>>(Ob, WoT, (void*)out,
                                                              MM, D_EMB, D_EMB, 1.0f);
}